// Round 6
// baseline (199.587 us; speedup 1.0000x reference)
//
#include <hip/hip_runtime.h>
#include <hip/hip_bf16.h>

// Problem constants (reference: InterpretableMultiHeadAttention)
#define NHEAD  8
#define DHEAD  64
#define HIDDEN 512
#define SEQ_T  2048
#define BATCH  4
#define NQKV   1088          // (2*8+1)*64
#define NT     32            // 2048/64 k-tiles
#define NROWS  (BATCH * SEQ_T)   // 8192
#define NBH    (BATCH * NHEAD)   // 32
#define QSC    (0.125f * 1.44269504f)   // qk-scale * log2(e), folded into Q

typedef __attribute__((ext_vector_type(8))) short short8;   // 8 x bf16 (4 VGPRs)
typedef __attribute__((ext_vector_type(4))) float f32x4;

// round-to-nearest-even f32 -> bf16 (finite inputs only)
__device__ __forceinline__ unsigned short f2bf(float f) {
  unsigned int u = __float_as_uint(f);
  u += 0x7FFFu + ((u >> 16) & 1u);
  return (unsigned short)(u >> 16);
}

__device__ __forceinline__ void load_lds16(const unsigned short* g, unsigned short* l) {
  __builtin_amdgcn_global_load_lds((const __attribute__((address_space(1))) void*)g,
                                   (__attribute__((address_space(3))) void*)l, 16, 0, 0);
}

// DPP butterfly sum over the 16-lane DPP row.
#define DPPF(x, ctrl) \
  __int_as_float(__builtin_amdgcn_update_dpp(0, __float_as_int(x), (ctrl), 0xF, 0xF, true))
__device__ __forceinline__ float rsum16(float x) {
  x += DPPF(x, 0xB1);    // quad_perm xor1
  x += DPPF(x, 0x4E);    // quad_perm xor2
  x += DPPF(x, 0x141);   // row_half_mirror
  x += DPPF(x, 0x140);   // row_mirror
  return x;
}

// ---------------------------------------------------------------------------
// Prep (fused): blocks [0,2048): x fp32->bf16.  blocks [2048,2184): Wt.
// ---------------------------------------------------------------------------
__global__ __launch_bounds__(256) void prep(const float* __restrict__ x,
                                            const float* __restrict__ W,
                                            unsigned short* __restrict__ xb,
                                            unsigned short* __restrict__ Wt) {
  const int bx = blockIdx.x;
  const int tid = threadIdx.x;
  if (bx < 2048) {
    const size_t i0 = ((size_t)bx * 256 + tid) * 8;
    float4 a = *(const float4*)(x + i0);
    float4 b = *(const float4*)(x + i0 + 4);
    ushort4 u0, u1;
    u0.x = f2bf(a.x); u0.y = f2bf(a.y); u0.z = f2bf(a.z); u0.w = f2bf(a.w);
    u1.x = f2bf(b.x); u1.y = f2bf(b.y); u1.z = f2bf(b.z); u1.w = f2bf(b.w);
    *(ushort4*)(xb + i0) = u0;
    *(ushort4*)(xb + i0 + 4) = u1;
    return;
  }
  // Wt[n][k] = bf16(W[k][n]) via 64x64 LDS transpose
  const int idx = bx - 2048;          // 0..135
  const int n0 = (idx % 17) * 64;
  const int k0 = (idx / 17) * 64;
  __shared__ float T[64 * 65];
#pragma unroll
  for (int i = 0; i < 4; ++i) {
    int f = tid + i * 256;
    int r = f >> 4;
    int c4 = (f & 15) * 4;
    float4 v = *(const float4*)(W + (size_t)(k0 + r) * NQKV + n0 + c4);
    T[r * 65 + c4 + 0] = v.x;
    T[r * 65 + c4 + 1] = v.y;
    T[r * 65 + c4 + 2] = v.z;
    T[r * 65 + c4 + 3] = v.w;
  }
  __syncthreads();
#pragma unroll
  for (int i = 0; i < 4; ++i) {
    int f = tid + i * 256;
    int n = f >> 4;
    int k4 = (f & 15) * 4;
    ushort4 u;
    u.x = f2bf(T[(k4 + 0) * 65 + n]);
    u.y = f2bf(T[(k4 + 1) * 65 + n]);
    u.z = f2bf(T[(k4 + 2) * 65 + n]);
    u.w = f2bf(T[(k4 + 3) * 65 + n]);
    *(ushort4*)(Wt + (size_t)(n0 + n) * HIDDEN + k0 + k4) = u;
  }
}

// ---------------------------------------------------------------------------
// Kernel 1: qkv = xb @ Wt^T via bf16 MFMA.  XCD-aware 1D swizzle.
// Q columns (bn<8) pre-scaled by QSC.
// ---------------------------------------------------------------------------
__global__ __launch_bounds__(256) void qkv_mfma(const unsigned short* __restrict__ Xb,
                                                const unsigned short* __restrict__ Wt,
                                                unsigned short* __restrict__ Y) {
  __shared__ __align__(16) unsigned short As[128 * 64];
  __shared__ __align__(16) unsigned short Bs[64 * 64];
  const int L = blockIdx.x;       // 0..1087
  const int slot = L >> 3;        // 0..135
  const int bm = (L & 7) * 8 + (slot & 7);   // 0..63
  const int bn = slot >> 3;                  // 0..16
  const int tid = threadIdx.x;
  const int wave = tid >> 6;
  const int lane = tid & 63;
  const int quad = lane >> 4;
  const int l15 = lane & 15;
  const int lrow = lane >> 3;
  const int lchunk = lane & 7;

  const unsigned short* xrow = Xb + (size_t)bm * 128 * HIDDEN;
  const unsigned short* wrow = Wt + (size_t)bn * 64 * HIDDEN;

  f32x4 acc[2][4];
#pragma unroll
  for (int mt = 0; mt < 2; ++mt)
#pragma unroll
    for (int nt = 0; nt < 4; ++nt) acc[mt][nt] = (f32x4){0.f, 0.f, 0.f, 0.f};

  for (int k0 = 0; k0 < HIDDEN; k0 += 64) {
    __syncthreads();
#pragma unroll
    for (int c = 0; c < 4; ++c) {
      int call = wave * 4 + c;
      int m = call * 8 + lrow;
      int clog = lchunk ^ lrow;
      load_lds16(xrow + (size_t)m * HIDDEN + k0 + clog * 8, &As[call * 512]);
    }
#pragma unroll
    for (int c = 0; c < 2; ++c) {
      int call = wave * 2 + c;
      int n = call * 8 + lrow;
      int clog = lchunk ^ lrow;
      load_lds16(wrow + (size_t)n * HIDDEN + k0 + clog * 8, &Bs[call * 512]);
    }
    __syncthreads();

#pragma unroll
    for (int ks = 0; ks < 2; ++ks) {
      short8 a[2], b[4];
#pragma unroll
      for (int mt = 0; mt < 2; ++mt) {
        int m = wave * 32 + mt * 16 + l15;
        int phys = (ks * 4 + quad) ^ (l15 & 7);
        a[mt] = *(const short8*)&As[m * 64 + phys * 8];
      }
#pragma unroll
      for (int nt = 0; nt < 4; ++nt) {
        int n = nt * 16 + l15;
        int phys = (ks * 4 + quad) ^ (l15 & 7);
        b[nt] = *(const short8*)&Bs[n * 64 + phys * 8];
      }
#pragma unroll
      for (int mt = 0; mt < 2; ++mt)
#pragma unroll
        for (int nt = 0; nt < 4; ++nt)
          acc[mt][nt] = __builtin_amdgcn_mfma_f32_16x16x32_bf16(a[mt], b[nt], acc[mt][nt], 0, 0, 0);
    }
  }

  const float qs = (bn < 8) ? QSC : 1.0f;   // pre-scale Q region
#pragma unroll
  for (int mt = 0; mt < 2; ++mt)
#pragma unroll
    for (int r = 0; r < 4; ++r) {
      int row = bm * 128 + wave * 32 + mt * 16 + quad * 4 + r;
#pragma unroll
      for (int nt = 0; nt < 4; ++nt) {
        int col = bn * 64 + nt * 16 + l15;
        Y[(size_t)row * NQKV + col] = f2bf(acc[mt][nt][r] * qs);
      }
    }
}

// ---------------------------------------------------------------------------
// Kernel 2: vt[b][d][k0+n] = V[b][k0+pi(n)][d], pi(n) = 16*(n&3) + (n>>2).
// Same permutation applied to P storage cols in attn_pass -> P.V invariant.
// ---------------------------------------------------------------------------
__global__ __launch_bounds__(256) void v_transpose(const unsigned short* __restrict__ qkv,
                                                   unsigned short* __restrict__ vt) {
  const int b = blockIdx.x >> 5;
  const int k0 = (blockIdx.x & 31) * 64;
  const int tid = threadIdx.x;
  __shared__ unsigned short Vs[64 * 66];

#pragma unroll
  for (int i = 0; i < 8; ++i) {
    int c = tid + i * 256;
    int row = c >> 5;
    int col2 = c & 31;
    unsigned int v = *(const unsigned int*)(qkv + (size_t)(b * SEQ_T + k0 + row) * NQKV + 1024 + col2 * 2);
    *(unsigned int*)&Vs[row * 66 + col2 * 2] = v;
  }
  __syncthreads();

#pragma unroll
  for (int i = 0; i < 16; ++i) {
    int f = tid + i * 256;
    int d = f >> 6;
    int n = f & 63;
    int c = ((n & 3) << 4) | (n >> 2);   // pi(n): true kcol
    vt[((size_t)b * DHEAD + d) * SEQ_T + k0 + n] = Vs[c * 66 + d];
  }
}

// ---------------------------------------------------------------------------
// Kernel 3: flash attention pass, streaming softmax, k-split.
// Register-prefetch staging: next K/V tile loaded to VGPRs during compute,
// ds_write'd at iter start -> barriers no longer drain fresh global loads.
// ---------------------------------------------------------------------------
__global__ __launch_bounds__(256, 4) void attn_pass(const unsigned short* __restrict__ qkv,
                                                    const unsigned short* __restrict__ vt,
                                                    float* __restrict__ part0,
                                                    unsigned short* __restrict__ pbuf,
                                                    float* __restrict__ lbuf) {
  const int bh = blockIdx.x;       // 0..31
  const int y = blockIdx.y;        // 0..31
  const int qt = 15 - (y >> 1);    // big tiles dispatched first
  const int kh = y & 1;
  const int b = bh >> 3;
  const int h = bh & 7;
  const int tid = threadIdx.x;
  const int wave = tid >> 6;
  const int lane = tid & 63;
  const int quad = lane >> 4;
  const int l15 = lane & 15;

  __shared__ __align__(16) unsigned short Ks[64 * 64];   // XOR-swizzled chunks
  __shared__ __align__(16) unsigned short Vts[64 * 64];  // XOR-swizzled chunks
  __shared__ __align__(16) unsigned short Ps[128 * 72];  // pitch 72, permuted cols

  const unsigned short* bq = qkv + (size_t)b * SEQ_T * NQKV;
  const unsigned short* bvt = vt + (size_t)b * DHEAD * SEQ_T;

  const int q0 = qt * 128;
  const int kbeg = kh ? (qt + 1) : 0;
  const int kend = kh ? (2 * qt + 1) : qt;  // inclusive

  // Q A-frags for both strips (pre-scaled by QSC in qkv_mfma)
  short8 aq[2][2];
#pragma unroll
  for (int s = 0; s < 2; ++s) {
    const unsigned short* qp = bq + (size_t)(q0 + s * 64 + wave * 16 + l15) * NQKV + h * 64 + quad * 8;
    aq[s][0] = *(const short8*)qp;
    aq[s][1] = *(const short8*)(qp + 32);
  }

  f32x4 o[2][4];
#pragma unroll
  for (int s = 0; s < 2; ++s)
#pragma unroll
    for (int t = 0; t < 4; ++t) o[s][t] = (f32x4){0.f, 0.f, 0.f, 0.f};
  float l_part[2][4] = {{0.f, 0.f, 0.f, 0.f}, {0.f, 0.f, 0.f, 0.f}};

  const int srow = tid >> 3;               // 0..31 staging row-within-call
  const int sch = (tid & 7) ^ (srow & 7);  // logical chunk to fetch
  const int ph0 = (quad ^ (l15 & 7)) * 8;  // frag-read physical chunk offset
  const int lslot = wave * 512 + lane * 8; // this thread's 16B LDS slot

  // prologue prefetch of first tile
  uint4 kpref[2], vpref[2];
#pragma unroll
  for (int c = 0; c < 2; ++c) {
    kpref[c] = *(const uint4*)(bq + (size_t)(kbeg * 64 + c * 32 + srow) * NQKV + 512 + h * 64 + sch * 8);
    vpref[c] = *(const uint4*)(bvt + (size_t)(c * 32 + srow) * SEQ_T + kbeg * 64 + sch * 8);
  }

  for (int kt = kbeg; kt <= kend; ++kt) {
    const int k0 = kt * 64;
    __syncthreads();                  // prior iter done reading LDS
#pragma unroll
    for (int c = 0; c < 2; ++c) {
      *(uint4*)&Ks[c * 2048 + lslot] = kpref[c];
      *(uint4*)&Vts[c * 2048 + lslot] = vpref[c];
    }
    if (kt < kend) {                  // prefetch next tile (lands during compute)
      const int kn = (kt + 1) * 64;
#pragma unroll
      for (int c = 0; c < 2; ++c) {
        kpref[c] = *(const uint4*)(bq + (size_t)(kn + c * 32 + srow) * NQKV + 512 + h * 64 + sch * 8);
        vpref[c] = *(const uint4*)(bvt + (size_t)(c * 32 + srow) * SEQ_T + kn + sch * 8);
      }
    }
    __syncthreads();                  // staging visible (lgkm only, no vm drain)

    const bool needMask = (k0 + 63) > q0;

    // ---- K B-frags once (shared by both strips)
    short8 bk[4][2];
#pragma unroll
    for (int t = 0; t < 4; ++t) {
      const unsigned short* kp = &Ks[(l15 + 16 * t) * 64];
      bk[t][0] = *(const short8*)(kp + ph0);
      bk[t][1] = *(const short8*)(kp + (ph0 ^ 32));
    }

    // ---- per strip: S = Q K^T -> exp2 -> packed P store
#pragma unroll
    for (int s = 0; s < 2; ++s) {
      f32x4 pr[4];
#pragma unroll
      for (int t = 0; t < 4; ++t) {
        f32x4 sv = (f32x4){0.f, 0.f, 0.f, 0.f};
        sv = __builtin_amdgcn_mfma_f32_16x16x32_bf16(aq[s][0], bk[t][0], sv, 0, 0, 0);
        sv = __builtin_amdgcn_mfma_f32_16x16x32_bf16(aq[s][1], bk[t][1], sv, 0, 0, 0);
        pr[t] = sv;
      }
      const int rbase = s * 64 + wave * 16 + quad * 4;
#pragma unroll
      for (int t = 0; t < 4; ++t)
#pragma unroll
        for (int r = 0; r < 4; ++r) {
          float p = __builtin_amdgcn_exp2f(pr[t][r]);
          if (needMask)
            p = (k0 + 16 * t + l15 <= q0 + rbase + r) ? p : 0.f;
          l_part[s][r] += p;
          pr[t][r] = p;
        }
      // pack 4 t-values (contiguous permuted cols 4*l15..+4) -> b64 store
#pragma unroll
      for (int r = 0; r < 4; ++r) {
        uint2 w;
        w.x = __builtin_amdgcn_perm(__float_as_uint(pr[1][r]), __float_as_uint(pr[0][r]), 0x07060302u);
        w.y = __builtin_amdgcn_perm(__float_as_uint(pr[3][r]), __float_as_uint(pr[2][r]), 0x07060302u);
        *(uint2*)&Ps[(rbase + r) * 72 + 4 * l15] = w;
      }
    }

    // ---- V^T B-frags + P A-frags (wave-internal dep for Ps; no barrier)
    short8 bv[4][2];
#pragma unroll
    for (int t = 0; t < 4; ++t) {
      const unsigned short* vp = &Vts[(l15 + 16 * t) * 64];
      bv[t][0] = *(const short8*)(vp + ph0);
      bv[t][1] = *(const short8*)(vp + (ph0 ^ 32));
    }
    short8 ap[2][2];
#pragma unroll
    for (int s = 0; s < 2; ++s) {
      const unsigned short* pp = &Ps[(s * 64 + wave * 16 + l15) * 72];
      ap[s][0] = *(const short8*)(pp + quad * 8);
      ap[s][1] = *(const short8*)(pp + 32 + quad * 8);
    }

    // ---- O += P V
#pragma unroll
    for (int t = 0; t < 4; ++t)
#pragma unroll
      for (int s = 0; s < 2; ++s) {
        o[s][t] = __builtin_amdgcn_mfma_f32_16x16x32_bf16(ap[s][0], bv[t][0], o[s][t], 0, 0, 0);
        o[s][t] = __builtin_amdgcn_mfma_f32_16x16x32_bf16(ap[s][1], bv[t][1], o[s][t], 0, 0, 0);
      }
  }

  // ---- epilogue: raw partial O + per-row l (division happens in out_merge)
#pragma unroll
  for (int s = 0; s < 2; ++s) {
#pragma unroll
    for (int r = 0; r < 4; ++r) {
      float l = rsum16(l_part[s][r]);
      const int trow = q0 + s * 64 + wave * 16 + quad * 4 + r;
      if (l15 == 0) lbuf[kh * (NBH * SEQ_T) + bh * SEQ_T + trow] = l;
      const size_t base = ((size_t)bh * SEQ_T + trow) * DHEAD;
      if (kh == 0) {
#pragma unroll
        for (int t = 0; t < 4; ++t) part0[base + l15 + 16 * t] = o[s][t][r];
      } else {
#pragma unroll
        for (int t = 0; t < 4; ++t) pbuf[base + l15 + 16 * t] = f2bf(o[s][t][r]);
      }
    }
  }
}

// ---------------------------------------------------------------------------
// Kernel 4 (fused): attn_vec = (O0+O1)/(l0+l1); out = mean_h(attn_vec) @ W_out
// ---------------------------------------------------------------------------
__global__ __launch_bounds__(256) void out_merge(const float* __restrict__ part0,
                                                 const unsigned short* __restrict__ pbuf,
                                                 const float* __restrict__ lbuf,
                                                 const float* __restrict__ Wout,
                                                 float* __restrict__ attnv,
                                                 float* __restrict__ out) {
  const int row0 = blockIdx.x * 16;   // global row = b*2048 + t
  const int tid = threadIdx.x;
  __shared__ float Ms[16][64];

#pragma unroll
  for (int i = 0; i < 4; ++i) {
    int f = tid + i * 256;
    int lr = f >> 6;
    int d = f & 63;
    int row = row0 + lr;
    int b = row >> 11;
    int t = row & 2047;
    float sum = 0.f;
#pragma unroll
    for (int hh = 0; hh < NHEAD; ++hh) {
      size_t ridx = (size_t)(b * NHEAD + hh) * SEQ_T + t;
      float inv = 1.0f / (lbuf[ridx] + lbuf[NBH * SEQ_T + ridx]);
      size_t idx = ridx * DHEAD + d;
      float m = (part0[idx] + __uint_as_float((unsigned int)pbuf[idx] << 16)) * inv;
      attnv[idx] = m;
      sum += m;
    }
    Ms[lr][d] = sum * (1.0f / NHEAD);
  }
  __syncthreads();

  const int c0 = tid * 2;
  float a0[16], a1[16];
#pragma unroll
  for (int i = 0; i < 16; ++i) { a0[i] = 0.f; a1[i] = 0.f; }

  for (int d = 0; d < 64; ++d) {
    float2 w = *(const float2*)(Wout + (size_t)d * HIDDEN + c0);
#pragma unroll
    for (int lr = 0; lr < 16; ++lr) {
      float m = Ms[lr][d];
      a0[lr] += m * w.x;
      a1[lr] += m * w.y;
    }
  }
#pragma unroll
  for (int lr = 0; lr < 16; ++lr) {
    float2 v = make_float2(a0[lr], a1[lr]);
    *(float2*)(out + (size_t)(row0 + lr) * HIDDEN + c0) = v;
  }
}

// ---------------------------------------------------------------------------
extern "C" void kernel_launch(void* const* d_in, const int* in_sizes, int n_in,
                              void* d_out, int out_size, void* d_ws, size_t ws_size,
                              hipStream_t stream) {
  const float* x     = (const float*)d_in[0];   // (4,2048,512)
  const float* W_qkv = (const float*)d_in[1];   // (512,1088)
  const float* W_out = (const float*)d_in[2];   // (64,512)

  float* out      = (float*)d_out;                              // (4,2048,512)
  float* attn_vec = out + (size_t)BATCH * SEQ_T * HIDDEN;       // (4,8,2048,64)

  unsigned short* qkv = (unsigned short*)d_ws;                  // 17.8 MB bf16
  unsigned short* vt  = qkv + (size_t)NROWS * NQKV;             // 1.0 MB bf16
  unsigned short* xb  = vt + (size_t)BATCH * DHEAD * SEQ_T;     // 8.4 MB bf16
  unsigned short* Wt  = xb + (size_t)NROWS * HIDDEN;            // 1.1 MB bf16
  // xb and Wt are dead after qkv_mfma -> overlay attention partials there
  unsigned short* pbuf = xb;                                    // bf16 partial O
  float*          lbuf = (float*)Wt;                            // 2 x 65536 l sums

  prep<<<dim3(2048 + 136), 256, 0, stream>>>(x, W_qkv, xb, Wt);
  qkv_mfma<<<dim3(64 * 17), 256, 0, stream>>>(xb, Wt, qkv);
  v_transpose<<<dim3(BATCH * NT), 256, 0, stream>>>(qkv, vt);
  attn_pass<<<dim3(NBH, 32), 256, 0, stream>>>(qkv, vt, attn_vec, pbuf, lbuf);
  out_merge<<<dim3(512), 256, 0, stream>>>(attn_vec, pbuf, lbuf, W_out, attn_vec, out);
}

// Round 7
// 147.427 us; speedup vs baseline: 1.3538x; 1.3538x over previous
//
#include <hip/hip_runtime.h>
#include <hip/hip_bf16.h>

// Problem constants (reference: InterpretableMultiHeadAttention)
#define NHEAD  8
#define DHEAD  64
#define HIDDEN 512
#define SEQ_T  2048
#define BATCH  4
#define NQKV   1088          // (2*8+1)*64
#define NT     32            // 2048/64 k-tiles
#define NROWS  (BATCH * SEQ_T)   // 8192
#define NBH    (BATCH * NHEAD)   // 32
#define QSC    (0.125f * 1.44269504f)   // qk-scale * log2(e), folded into Q

typedef __attribute__((ext_vector_type(8))) short short8;   // 8 x bf16 (4 VGPRs)
typedef __attribute__((ext_vector_type(4))) float f32x4;

// round-to-nearest-even f32 -> bf16 (finite inputs only)
__device__ __forceinline__ unsigned short f2bf(float f) {
  unsigned int u = __float_as_uint(f);
  u += 0x7FFFu + ((u >> 16) & 1u);
  return (unsigned short)(u >> 16);
}

__device__ __forceinline__ void load_lds16(const unsigned short* g, unsigned short* l) {
  __builtin_amdgcn_global_load_lds((const __attribute__((address_space(1))) void*)g,
                                   (__attribute__((address_space(3))) void*)l, 16, 0, 0);
}

// DPP butterfly sum over the 16-lane DPP row.
#define DPPF(x, ctrl) \
  __int_as_float(__builtin_amdgcn_update_dpp(0, __float_as_int(x), (ctrl), 0xF, 0xF, true))
__device__ __forceinline__ float rsum16(float x) {
  x += DPPF(x, 0xB1);    // quad_perm xor1
  x += DPPF(x, 0x4E);    // quad_perm xor2
  x += DPPF(x, 0x141);   // row_half_mirror
  x += DPPF(x, 0x140);   // row_mirror
  return x;
}

// ---------------------------------------------------------------------------
// Prep (fused): blocks [0,2048): x fp32->bf16.  blocks [2048,2184): Wt.
// ---------------------------------------------------------------------------
__global__ __launch_bounds__(256) void prep(const float* __restrict__ x,
                                            const float* __restrict__ W,
                                            unsigned short* __restrict__ xb,
                                            unsigned short* __restrict__ Wt) {
  const int bx = blockIdx.x;
  const int tid = threadIdx.x;
  if (bx < 2048) {
    const size_t i0 = ((size_t)bx * 256 + tid) * 8;
    float4 a = *(const float4*)(x + i0);
    float4 b = *(const float4*)(x + i0 + 4);
    ushort4 u0, u1;
    u0.x = f2bf(a.x); u0.y = f2bf(a.y); u0.z = f2bf(a.z); u0.w = f2bf(a.w);
    u1.x = f2bf(b.x); u1.y = f2bf(b.y); u1.z = f2bf(b.z); u1.w = f2bf(b.w);
    *(ushort4*)(xb + i0) = u0;
    *(ushort4*)(xb + i0 + 4) = u1;
    return;
  }
  // Wt[n][k] = bf16(W[k][n]) via 64x64 LDS transpose
  const int idx = bx - 2048;          // 0..135
  const int n0 = (idx % 17) * 64;
  const int k0 = (idx / 17) * 64;
  __shared__ float T[64 * 65];
#pragma unroll
  for (int i = 0; i < 4; ++i) {
    int f = tid + i * 256;
    int r = f >> 4;
    int c4 = (f & 15) * 4;
    float4 v = *(const float4*)(W + (size_t)(k0 + r) * NQKV + n0 + c4);
    T[r * 65 + c4 + 0] = v.x;
    T[r * 65 + c4 + 1] = v.y;
    T[r * 65 + c4 + 2] = v.z;
    T[r * 65 + c4 + 3] = v.w;
  }
  __syncthreads();
#pragma unroll
  for (int i = 0; i < 4; ++i) {
    int f = tid + i * 256;
    int n = f >> 4;
    int k4 = (f & 15) * 4;
    ushort4 u;
    u.x = f2bf(T[(k4 + 0) * 65 + n]);
    u.y = f2bf(T[(k4 + 1) * 65 + n]);
    u.z = f2bf(T[(k4 + 2) * 65 + n]);
    u.w = f2bf(T[(k4 + 3) * 65 + n]);
    *(ushort4*)(Wt + (size_t)(n0 + n) * HIDDEN + k0 + k4) = u;
  }
}

// ---------------------------------------------------------------------------
// Kernel 1: qkv = xb @ Wt^T via bf16 MFMA.  XCD-aware 1D swizzle.
// Q columns (bn<8) pre-scaled by QSC.
// ---------------------------------------------------------------------------
__global__ __launch_bounds__(256) void qkv_mfma(const unsigned short* __restrict__ Xb,
                                                const unsigned short* __restrict__ Wt,
                                                unsigned short* __restrict__ Y) {
  __shared__ __align__(16) unsigned short As[128 * 64];
  __shared__ __align__(16) unsigned short Bs[64 * 64];
  const int L = blockIdx.x;       // 0..1087
  const int slot = L >> 3;        // 0..135
  const int bm = (L & 7) * 8 + (slot & 7);   // 0..63
  const int bn = slot >> 3;                  // 0..16
  const int tid = threadIdx.x;
  const int wave = tid >> 6;
  const int lane = tid & 63;
  const int quad = lane >> 4;
  const int l15 = lane & 15;
  const int lrow = lane >> 3;
  const int lchunk = lane & 7;

  const unsigned short* xrow = Xb + (size_t)bm * 128 * HIDDEN;
  const unsigned short* wrow = Wt + (size_t)bn * 64 * HIDDEN;

  f32x4 acc[2][4];
#pragma unroll
  for (int mt = 0; mt < 2; ++mt)
#pragma unroll
    for (int nt = 0; nt < 4; ++nt) acc[mt][nt] = (f32x4){0.f, 0.f, 0.f, 0.f};

  for (int k0 = 0; k0 < HIDDEN; k0 += 64) {
    __syncthreads();
#pragma unroll
    for (int c = 0; c < 4; ++c) {
      int call = wave * 4 + c;
      int m = call * 8 + lrow;
      int clog = lchunk ^ lrow;
      load_lds16(xrow + (size_t)m * HIDDEN + k0 + clog * 8, &As[call * 512]);
    }
#pragma unroll
    for (int c = 0; c < 2; ++c) {
      int call = wave * 2 + c;
      int n = call * 8 + lrow;
      int clog = lchunk ^ lrow;
      load_lds16(wrow + (size_t)n * HIDDEN + k0 + clog * 8, &Bs[call * 512]);
    }
    __syncthreads();

#pragma unroll
    for (int ks = 0; ks < 2; ++ks) {
      short8 a[2], b[4];
#pragma unroll
      for (int mt = 0; mt < 2; ++mt) {
        int m = wave * 32 + mt * 16 + l15;
        int phys = (ks * 4 + quad) ^ (l15 & 7);
        a[mt] = *(const short8*)&As[m * 64 + phys * 8];
      }
#pragma unroll
      for (int nt = 0; nt < 4; ++nt) {
        int n = nt * 16 + l15;
        int phys = (ks * 4 + quad) ^ (l15 & 7);
        b[nt] = *(const short8*)&Bs[n * 64 + phys * 8];
      }
#pragma unroll
      for (int mt = 0; mt < 2; ++mt)
#pragma unroll
        for (int nt = 0; nt < 4; ++nt)
          acc[mt][nt] = __builtin_amdgcn_mfma_f32_16x16x32_bf16(a[mt], b[nt], acc[mt][nt], 0, 0, 0);
    }
  }

  const float qs = (bn < 8) ? QSC : 1.0f;   // pre-scale Q region
#pragma unroll
  for (int mt = 0; mt < 2; ++mt)
#pragma unroll
    for (int r = 0; r < 4; ++r) {
      int row = bm * 128 + wave * 32 + mt * 16 + quad * 4 + r;
#pragma unroll
      for (int nt = 0; nt < 4; ++nt) {
        int col = bn * 64 + nt * 16 + l15;
        Y[(size_t)row * NQKV + col] = f2bf(acc[mt][nt][r] * qs);
      }
    }
}

// ---------------------------------------------------------------------------
// Kernel 2: vt[b][d][k0+n] = V[b][k0+pi(n)][d], pi(n) = 16*(n&3) + (n>>2).
// Same permutation applied to P storage cols in attn_pass -> P.V invariant.
// ---------------------------------------------------------------------------
__global__ __launch_bounds__(256) void v_transpose(const unsigned short* __restrict__ qkv,
                                                   unsigned short* __restrict__ vt) {
  const int b = blockIdx.x >> 5;
  const int k0 = (blockIdx.x & 31) * 64;
  const int tid = threadIdx.x;
  __shared__ unsigned short Vs[64 * 66];

#pragma unroll
  for (int i = 0; i < 8; ++i) {
    int c = tid + i * 256;
    int row = c >> 5;
    int col2 = c & 31;
    unsigned int v = *(const unsigned int*)(qkv + (size_t)(b * SEQ_T + k0 + row) * NQKV + 1024 + col2 * 2);
    *(unsigned int*)&Vs[row * 66 + col2 * 2] = v;
  }
  __syncthreads();

#pragma unroll
  for (int i = 0; i < 16; ++i) {
    int f = tid + i * 256;
    int d = f >> 6;
    int n = f & 63;
    int c = ((n & 3) << 4) | (n >> 2);   // pi(n): true kcol
    vt[((size_t)b * DHEAD + d) * SEQ_T + k0 + n] = Vs[c * 66 + d];
  }
}

// ---------------------------------------------------------------------------
// Kernel 3: flash attention pass, streaming softmax, k-split.
// Double-buffered K/V LDS fed by global_load_lds (zero VGPR staging):
// ONE barrier per iter; its vmcnt drain waits on loads issued a full
// compute-phase ago. Loads for kt+1 issued right AFTER the barrier.
// ---------------------------------------------------------------------------
__global__ __launch_bounds__(256, 3) void attn_pass(const unsigned short* __restrict__ qkv,
                                                    const unsigned short* __restrict__ vt,
                                                    float* __restrict__ part0,
                                                    unsigned short* __restrict__ pbuf,
                                                    float* __restrict__ lbuf) {
  const int bh = blockIdx.x;       // 0..31
  const int y = blockIdx.y;        // 0..31
  const int qt = 15 - (y >> 1);    // big tiles dispatched first
  const int kh = y & 1;
  const int b = bh >> 3;
  const int h = bh & 7;
  const int tid = threadIdx.x;
  const int wave = tid >> 6;
  const int lane = tid & 63;
  const int quad = lane >> 4;
  const int l15 = lane & 15;

  __shared__ __align__(16) unsigned short Ks[2][64 * 64];   // XOR-swizzled chunks
  __shared__ __align__(16) unsigned short Vts[2][64 * 64];  // XOR-swizzled chunks
  __shared__ __align__(16) unsigned short Ps[128 * 72];     // pitch 72, permuted cols

  const unsigned short* bq = qkv + (size_t)b * SEQ_T * NQKV;
  const unsigned short* bvt = vt + (size_t)b * DHEAD * SEQ_T;

  const int q0 = qt * 128;
  const int kbeg = kh ? (qt + 1) : 0;
  const int kend = kh ? (2 * qt + 1) : qt;  // inclusive

  // Q A-frags for both strips (pre-scaled by QSC in qkv_mfma)
  short8 aq[2][2];
#pragma unroll
  for (int s = 0; s < 2; ++s) {
    const unsigned short* qp = bq + (size_t)(q0 + s * 64 + wave * 16 + l15) * NQKV + h * 64 + quad * 8;
    aq[s][0] = *(const short8*)qp;
    aq[s][1] = *(const short8*)(qp + 32);
  }

  f32x4 o[2][4];
#pragma unroll
  for (int s = 0; s < 2; ++s)
#pragma unroll
    for (int t = 0; t < 4; ++t) o[s][t] = (f32x4){0.f, 0.f, 0.f, 0.f};
  float l_part[2][4] = {{0.f, 0.f, 0.f, 0.f}, {0.f, 0.f, 0.f, 0.f}};

  const int srow = tid >> 3;               // 0..31 staging row-within-call
  const int sch = (tid & 7) ^ (srow & 7);  // logical chunk to fetch
  const int ph0 = (quad ^ (l15 & 7)) * 8;  // frag-read physical chunk offset

  // prologue: stage first tile into buffer 0
#pragma unroll
  for (int c = 0; c < 2; ++c) {
    load_lds16(bq + (size_t)(kbeg * 64 + c * 32 + srow) * NQKV + 512 + h * 64 + sch * 8,
               &Ks[0][c * 2048 + wave * 512]);
    load_lds16(bvt + (size_t)(c * 32 + srow) * SEQ_T + kbeg * 64 + sch * 8,
               &Vts[0][c * 2048 + wave * 512]);
  }

  for (int kt = kbeg; kt <= kend; ++kt) {
    const int k0 = kt * 64;
    const int cur = (kt - kbeg) & 1;
    __syncthreads();   // drains this wave's in-flight loads (cur buffer, issued
                       // one full iteration ago) + syncs waves off buf[cur^1]
    if (kt < kend) {   // stage next tile into the other buffer (post-barrier)
      const int kn = (kt + 1) * 64;
      const int nxt = cur ^ 1;
#pragma unroll
      for (int c = 0; c < 2; ++c) {
        load_lds16(bq + (size_t)(kn + c * 32 + srow) * NQKV + 512 + h * 64 + sch * 8,
                   &Ks[nxt][c * 2048 + wave * 512]);
        load_lds16(bvt + (size_t)(c * 32 + srow) * SEQ_T + kn + sch * 8,
                   &Vts[nxt][c * 2048 + wave * 512]);
      }
    }

    const unsigned short* ksb = Ks[cur];
    const unsigned short* vsb = Vts[cur];
    const bool needMask = (k0 + 63) > q0;

    // ---- K B-frags once (shared by both strips)
    short8 bk[4][2];
#pragma unroll
    for (int t = 0; t < 4; ++t) {
      const unsigned short* kp = &ksb[(l15 + 16 * t) * 64];
      bk[t][0] = *(const short8*)(kp + ph0);
      bk[t][1] = *(const short8*)(kp + (ph0 ^ 32));
    }

    // ---- per strip: S = Q K^T -> exp2 -> packed P store
#pragma unroll
    for (int s = 0; s < 2; ++s) {
      f32x4 pr[4];
#pragma unroll
      for (int t = 0; t < 4; ++t) {
        f32x4 sv = (f32x4){0.f, 0.f, 0.f, 0.f};
        sv = __builtin_amdgcn_mfma_f32_16x16x32_bf16(aq[s][0], bk[t][0], sv, 0, 0, 0);
        sv = __builtin_amdgcn_mfma_f32_16x16x32_bf16(aq[s][1], bk[t][1], sv, 0, 0, 0);
        pr[t] = sv;
      }
      const int rbase = s * 64 + wave * 16 + quad * 4;
#pragma unroll
      for (int t = 0; t < 4; ++t)
#pragma unroll
        for (int r = 0; r < 4; ++r) {
          float p = __builtin_amdgcn_exp2f(pr[t][r]);
          if (needMask)
            p = (k0 + 16 * t + l15 <= q0 + rbase + r) ? p : 0.f;
          l_part[s][r] += p;
          pr[t][r] = p;
        }
      // pack 4 t-values (contiguous permuted cols 4*l15..+4) -> b64 store
#pragma unroll
      for (int r = 0; r < 4; ++r) {
        uint2 w;
        w.x = __builtin_amdgcn_perm(__float_as_uint(pr[1][r]), __float_as_uint(pr[0][r]), 0x07060302u);
        w.y = __builtin_amdgcn_perm(__float_as_uint(pr[3][r]), __float_as_uint(pr[2][r]), 0x07060302u);
        *(uint2*)&Ps[(rbase + r) * 72 + 4 * l15] = w;
      }
    }

    // ---- V^T B-frags + P A-frags (wave-internal dep for Ps; no barrier)
    short8 bv[4][2];
#pragma unroll
    for (int t = 0; t < 4; ++t) {
      const unsigned short* vp = &vsb[(l15 + 16 * t) * 64];
      bv[t][0] = *(const short8*)(vp + ph0);
      bv[t][1] = *(const short8*)(vp + (ph0 ^ 32));
    }
    short8 ap[2][2];
#pragma unroll
    for (int s = 0; s < 2; ++s) {
      const unsigned short* pp = &Ps[(s * 64 + wave * 16 + l15) * 72];
      ap[s][0] = *(const short8*)(pp + quad * 8);
      ap[s][1] = *(const short8*)(pp + 32 + quad * 8);
    }

    // ---- O += P V
#pragma unroll
    for (int t = 0; t < 4; ++t)
#pragma unroll
      for (int s = 0; s < 2; ++s) {
        o[s][t] = __builtin_amdgcn_mfma_f32_16x16x32_bf16(ap[s][0], bv[t][0], o[s][t], 0, 0, 0);
        o[s][t] = __builtin_amdgcn_mfma_f32_16x16x32_bf16(ap[s][1], bv[t][1], o[s][t], 0, 0, 0);
      }
  }

  // ---- epilogue: raw partial O + per-row l (division happens in out_merge)
#pragma unroll
  for (int s = 0; s < 2; ++s) {
#pragma unroll
    for (int r = 0; r < 4; ++r) {
      float l = rsum16(l_part[s][r]);
      const int trow = q0 + s * 64 + wave * 16 + quad * 4 + r;
      if (l15 == 0) lbuf[kh * (NBH * SEQ_T) + bh * SEQ_T + trow] = l;
      const size_t base = ((size_t)bh * SEQ_T + trow) * DHEAD;
      if (kh == 0) {
#pragma unroll
        for (int t = 0; t < 4; ++t) part0[base + l15 + 16 * t] = o[s][t][r];
      } else {
#pragma unroll
        for (int t = 0; t < 4; ++t) pbuf[base + l15 + 16 * t] = f2bf(o[s][t][r]);
      }
    }
  }
}

// ---------------------------------------------------------------------------
// Kernel 4 (fused): attn_vec = (O0+O1)/(l0+l1); out = mean_h(attn_vec) @ W_out
// ---------------------------------------------------------------------------
__global__ __launch_bounds__(256) void out_merge(const float* __restrict__ part0,
                                                 const unsigned short* __restrict__ pbuf,
                                                 const float* __restrict__ lbuf,
                                                 const float* __restrict__ Wout,
                                                 float* __restrict__ attnv,
                                                 float* __restrict__ out) {
  const int row0 = blockIdx.x * 16;   // global row = b*2048 + t
  const int tid = threadIdx.x;
  __shared__ float Ms[16][64];

#pragma unroll
  for (int i = 0; i < 4; ++i) {
    int f = tid + i * 256;
    int lr = f >> 6;
    int d = f & 63;
    int row = row0 + lr;
    int b = row >> 11;
    int t = row & 2047;
    float sum = 0.f;
#pragma unroll
    for (int hh = 0; hh < NHEAD; ++hh) {
      size_t ridx = (size_t)(b * NHEAD + hh) * SEQ_T + t;
      float inv = 1.0f / (lbuf[ridx] + lbuf[NBH * SEQ_T + ridx]);
      size_t idx = ridx * DHEAD + d;
      float m = (part0[idx] + __uint_as_float((unsigned int)pbuf[idx] << 16)) * inv;
      attnv[idx] = m;
      sum += m;
    }
    Ms[lr][d] = sum * (1.0f / NHEAD);
  }
  __syncthreads();

  const int c0 = tid * 2;
  float a0[16], a1[16];
#pragma unroll
  for (int i = 0; i < 16; ++i) { a0[i] = 0.f; a1[i] = 0.f; }

  for (int d = 0; d < 64; ++d) {
    float2 w = *(const float2*)(Wout + (size_t)d * HIDDEN + c0);
#pragma unroll
    for (int lr = 0; lr < 16; ++lr) {
      float m = Ms[lr][d];
      a0[lr] += m * w.x;
      a1[lr] += m * w.y;
    }
  }
#pragma unroll
  for (int lr = 0; lr < 16; ++lr) {
    float2 v = make_float2(a0[lr], a1[lr]);
    *(float2*)(out + (size_t)(row0 + lr) * HIDDEN + c0) = v;
  }
}

// ---------------------------------------------------------------------------
extern "C" void kernel_launch(void* const* d_in, const int* in_sizes, int n_in,
                              void* d_out, int out_size, void* d_ws, size_t ws_size,
                              hipStream_t stream) {
  const float* x     = (const float*)d_in[0];   // (4,2048,512)
  const float* W_qkv = (const float*)d_in[1];   // (512,1088)
  const float* W_out = (const float*)d_in[2];   // (64,512)

  float* out      = (float*)d_out;                              // (4,2048,512)
  float* attn_vec = out + (size_t)BATCH * SEQ_T * HIDDEN;       // (4,8,2048,64)

  unsigned short* qkv = (unsigned short*)d_ws;                  // 17.8 MB bf16
  unsigned short* vt  = qkv + (size_t)NROWS * NQKV;             // 1.0 MB bf16
  unsigned short* xb  = vt + (size_t)BATCH * DHEAD * SEQ_T;     // 8.4 MB bf16
  unsigned short* Wt  = xb + (size_t)NROWS * HIDDEN;            // 1.1 MB bf16
  // xb and Wt are dead after qkv_mfma -> overlay attention partials there
  unsigned short* pbuf = xb;                                    // bf16 partial O
  float*          lbuf = (float*)Wt;                            // 2 x 65536 l sums

  prep<<<dim3(2048 + 136), 256, 0, stream>>>(x, W_qkv, xb, Wt);
  qkv_mfma<<<dim3(64 * 17), 256, 0, stream>>>(xb, Wt, qkv);
  v_transpose<<<dim3(BATCH * NT), 256, 0, stream>>>(qkv, vt);
  attn_pass<<<dim3(NBH, 32), 256, 0, stream>>>(qkv, vt, attn_vec, pbuf, lbuf);
  out_merge<<<dim3(512), 256, 0, stream>>>(attn_vec, pbuf, lbuf, W_out, attn_vec, out);
}

// Round 8
// 140.860 us; speedup vs baseline: 1.4169x; 1.0466x over previous
//
#include <hip/hip_runtime.h>
#include <hip/hip_bf16.h>

// Problem constants (reference: InterpretableMultiHeadAttention)
#define NHEAD  8
#define DHEAD  64
#define HIDDEN 512
#define SEQ_T  2048
#define BATCH  4
#define NQKV   1088          // (2*8+1)*64 true width
#define QPITCH 1152          // padded to 9*128 for BN=128 GEMM tiles
#define NT     32            // 2048/64 k-tiles
#define NROWS  (BATCH * SEQ_T)   // 8192
#define NBH    (BATCH * NHEAD)   // 32
#define QSC    (0.125f * 1.44269504f)   // qk-scale * log2(e), folded into Q

typedef __attribute__((ext_vector_type(8))) short short8;   // 8 x bf16 (4 VGPRs)
typedef __attribute__((ext_vector_type(4))) float f32x4;

// round-to-nearest-even f32 -> bf16 (finite inputs only)
__device__ __forceinline__ unsigned short f2bf(float f) {
  unsigned int u = __float_as_uint(f);
  u += 0x7FFFu + ((u >> 16) & 1u);
  return (unsigned short)(u >> 16);
}
__device__ __forceinline__ float bf2f(unsigned short u) {
  return __uint_as_float((unsigned int)u << 16);
}

__device__ __forceinline__ void load_lds16(const unsigned short* g, unsigned short* l) {
  __builtin_amdgcn_global_load_lds((const __attribute__((address_space(1))) void*)g,
                                   (__attribute__((address_space(3))) void*)l, 16, 0, 0);
}

// DPP butterfly sum over the 16-lane DPP row.
#define DPPF(x, ctrl) \
  __int_as_float(__builtin_amdgcn_update_dpp(0, __float_as_int(x), (ctrl), 0xF, 0xF, true))
__device__ __forceinline__ float rsum16(float x) {
  x += DPPF(x, 0xB1);    // quad_perm xor1
  x += DPPF(x, 0x4E);    // quad_perm xor2
  x += DPPF(x, 0x141);   // row_half_mirror
  x += DPPF(x, 0x140);   // row_mirror
  return x;
}

// ---------------------------------------------------------------------------
// Prep (fused): [0,2048): x fp32->bf16. [2048,2184): Wt transpose.
// [2184,2192): zero Wt pad rows 1088..1151 (re-poisoned every launch).
// ---------------------------------------------------------------------------
__global__ __launch_bounds__(256) void prep(const float* __restrict__ x,
                                            const float* __restrict__ W,
                                            unsigned short* __restrict__ xb,
                                            unsigned short* __restrict__ Wt) {
  const int bx = blockIdx.x;
  const int tid = threadIdx.x;
  if (bx < 2048) {
    const size_t i0 = ((size_t)bx * 256 + tid) * 8;
    float4 a = *(const float4*)(x + i0);
    float4 b = *(const float4*)(x + i0 + 4);
    ushort4 u0, u1;
    u0.x = f2bf(a.x); u0.y = f2bf(a.y); u0.z = f2bf(a.z); u0.w = f2bf(a.w);
    u1.x = f2bf(b.x); u1.y = f2bf(b.y); u1.z = f2bf(b.z); u1.w = f2bf(b.w);
    *(ushort4*)(xb + i0) = u0;
    *(ushort4*)(xb + i0 + 4) = u1;
    return;
  }
  if (bx >= 2184) {   // zero-fill Wt rows [1088,1152)
    const int z = bx - 2184;          // 0..7
    const size_t base = (size_t)NQKV * HIDDEN + ((size_t)z * 256 + tid) * 16;
    uint4 zero = {0u, 0u, 0u, 0u};
    *(uint4*)(Wt + base) = zero;
    *(uint4*)(Wt + base + 8) = zero;
    return;
  }
  // Wt[n][k] = bf16(W[k][n]) via 64x64 LDS transpose
  const int idx = bx - 2048;          // 0..135
  const int n0 = (idx % 17) * 64;
  const int k0 = (idx / 17) * 64;
  __shared__ float T[64 * 65];
#pragma unroll
  for (int i = 0; i < 4; ++i) {
    int f = tid + i * 256;
    int r = f >> 4;
    int c4 = (f & 15) * 4;
    float4 v = *(const float4*)(W + (size_t)(k0 + r) * NQKV + n0 + c4);
    T[r * 65 + c4 + 0] = v.x;
    T[r * 65 + c4 + 1] = v.y;
    T[r * 65 + c4 + 2] = v.z;
    T[r * 65 + c4 + 3] = v.w;
  }
  __syncthreads();
#pragma unroll
  for (int i = 0; i < 4; ++i) {
    int f = tid + i * 256;
    int n = f >> 4;
    int k4 = (f & 15) * 4;
    ushort4 u;
    u.x = f2bf(T[(k4 + 0) * 65 + n]);
    u.y = f2bf(T[(k4 + 1) * 65 + n]);
    u.z = f2bf(T[(k4 + 2) * 65 + n]);
    u.w = f2bf(T[(k4 + 3) * 65 + n]);
    *(ushort4*)(Wt + (size_t)(n0 + n) * HIDDEN + k0 + k4) = u;
  }
}

// ---------------------------------------------------------------------------
// Kernel 1: qkv = xb @ Wt^T via bf16 MFMA.  BM=128, BN=128 (N padded 1152),
// BK=64.  XCD-aware 1D swizzle: XCD (L&7) owns bm in [8*xcd,8*xcd+8).
// Q columns (bn<4) pre-scaled by QSC.
// ---------------------------------------------------------------------------
__global__ __launch_bounds__(256, 3) void qkv_mfma(const unsigned short* __restrict__ Xb,
                                                   const unsigned short* __restrict__ Wt,
                                                   unsigned short* __restrict__ Y) {
  __shared__ __align__(16) unsigned short As[128 * 64];
  __shared__ __align__(16) unsigned short Bs[128 * 64];
  const int L = blockIdx.x;       // 0..575
  const int slot = L >> 3;        // 0..71
  const int bm = (L & 7) * 8 + (slot & 7);   // 0..63
  const int bn = slot >> 3;                  // 0..8
  const int tid = threadIdx.x;
  const int wave = tid >> 6;
  const int lane = tid & 63;
  const int quad = lane >> 4;
  const int l15 = lane & 15;
  const int lrow = lane >> 3;
  const int lchunk = lane & 7;

  const unsigned short* xrow = Xb + (size_t)bm * 128 * HIDDEN;
  const unsigned short* wrow = Wt + (size_t)bn * 128 * HIDDEN;

  f32x4 acc[2][8];
#pragma unroll
  for (int mt = 0; mt < 2; ++mt)
#pragma unroll
    for (int nt = 0; nt < 8; ++nt) acc[mt][nt] = (f32x4){0.f, 0.f, 0.f, 0.f};

  for (int k0 = 0; k0 < HIDDEN; k0 += 64) {
    __syncthreads();
#pragma unroll
    for (int c = 0; c < 4; ++c) {
      int call = wave * 4 + c;
      int m = call * 8 + lrow;
      int clog = lchunk ^ lrow;
      load_lds16(xrow + (size_t)m * HIDDEN + k0 + clog * 8, &As[call * 512]);
      load_lds16(wrow + (size_t)m * HIDDEN + k0 + clog * 8, &Bs[call * 512]);
    }
    __syncthreads();

#pragma unroll
    for (int ks = 0; ks < 2; ++ks) {
      short8 a[2], b[8];
#pragma unroll
      for (int mt = 0; mt < 2; ++mt) {
        int m = wave * 32 + mt * 16 + l15;
        int phys = (ks * 4 + quad) ^ (l15 & 7);
        a[mt] = *(const short8*)&As[m * 64 + phys * 8];
      }
#pragma unroll
      for (int nt = 0; nt < 8; ++nt) {
        int n = nt * 16 + l15;
        int phys = (ks * 4 + quad) ^ (l15 & 7);
        b[nt] = *(const short8*)&Bs[n * 64 + phys * 8];
      }
#pragma unroll
      for (int mt = 0; mt < 2; ++mt)
#pragma unroll
        for (int nt = 0; nt < 8; ++nt)
          acc[mt][nt] = __builtin_amdgcn_mfma_f32_16x16x32_bf16(a[mt], b[nt], acc[mt][nt], 0, 0, 0);
    }
  }

  const float qs = (bn < 4) ? QSC : 1.0f;   // pre-scale Q region (cols < 512)
#pragma unroll
  for (int mt = 0; mt < 2; ++mt)
#pragma unroll
    for (int r = 0; r < 4; ++r) {
      int row = bm * 128 + wave * 32 + mt * 16 + quad * 4 + r;
#pragma unroll
      for (int nt = 0; nt < 8; ++nt) {
        int col = bn * 128 + nt * 16 + l15;
        Y[(size_t)row * QPITCH + col] = f2bf(acc[mt][nt][r] * qs);
      }
    }
}

// ---------------------------------------------------------------------------
// Kernel 2: vt[b][d][k0+n] = V[b][k0+pi(n)][d], pi(n) = 16*(n&3) + (n>>2).
// Same permutation applied to P storage cols in attn_pass -> P.V invariant.
// ---------------------------------------------------------------------------
__global__ __launch_bounds__(256) void v_transpose(const unsigned short* __restrict__ qkv,
                                                   unsigned short* __restrict__ vt) {
  const int b = blockIdx.x >> 5;
  const int k0 = (blockIdx.x & 31) * 64;
  const int tid = threadIdx.x;
  __shared__ unsigned short Vs[64 * 66];

#pragma unroll
  for (int i = 0; i < 8; ++i) {
    int c = tid + i * 256;
    int row = c >> 5;
    int col2 = c & 31;
    unsigned int v = *(const unsigned int*)(qkv + (size_t)(b * SEQ_T + k0 + row) * QPITCH + 1024 + col2 * 2);
    *(unsigned int*)&Vs[row * 66 + col2 * 2] = v;
  }
  __syncthreads();

#pragma unroll
  for (int i = 0; i < 16; ++i) {
    int f = tid + i * 256;
    int d = f >> 6;
    int n = f & 63;
    int c = ((n & 3) << 4) | (n >> 2);   // pi(n): true kcol
    vt[((size_t)b * DHEAD + d) * SEQ_T + k0 + n] = Vs[c * 66 + d];
  }
}

// ---------------------------------------------------------------------------
// Kernel 3: flash attention pass, streaming softmax, k-split.
// Double-buffered K/V LDS fed by global_load_lds (zero VGPR staging):
// ONE barrier per iter; vmcnt drain targets loads issued a full compute
// phase ago. Both k-halves write bf16 partial O.
// ---------------------------------------------------------------------------
__global__ __launch_bounds__(256, 3) void attn_pass(const unsigned short* __restrict__ qkv,
                                                    const unsigned short* __restrict__ vt,
                                                    unsigned short* __restrict__ pbuf0,
                                                    unsigned short* __restrict__ pbuf1,
                                                    float* __restrict__ lbuf) {
  const int bh = blockIdx.x;       // 0..31
  const int y = blockIdx.y;        // 0..31
  const int qt = 15 - (y >> 1);    // big tiles dispatched first
  const int kh = y & 1;
  const int b = bh >> 3;
  const int h = bh & 7;
  const int tid = threadIdx.x;
  const int wave = tid >> 6;
  const int lane = tid & 63;
  const int quad = lane >> 4;
  const int l15 = lane & 15;

  __shared__ __align__(16) unsigned short Ks[2][64 * 64];   // XOR-swizzled chunks
  __shared__ __align__(16) unsigned short Vts[2][64 * 64];  // XOR-swizzled chunks
  __shared__ __align__(16) unsigned short Ps[128 * 72];     // pitch 72, permuted cols

  const unsigned short* bq = qkv + (size_t)b * SEQ_T * QPITCH;
  const unsigned short* bvt = vt + (size_t)b * DHEAD * SEQ_T;

  const int q0 = qt * 128;
  const int kbeg = kh ? (qt + 1) : 0;
  const int kend = kh ? (2 * qt + 1) : qt;  // inclusive

  // Q A-frags for both strips (pre-scaled by QSC in qkv_mfma)
  short8 aq[2][2];
#pragma unroll
  for (int s = 0; s < 2; ++s) {
    const unsigned short* qp = bq + (size_t)(q0 + s * 64 + wave * 16 + l15) * QPITCH + h * 64 + quad * 8;
    aq[s][0] = *(const short8*)qp;
    aq[s][1] = *(const short8*)(qp + 32);
  }

  f32x4 o[2][4];
#pragma unroll
  for (int s = 0; s < 2; ++s)
#pragma unroll
    for (int t = 0; t < 4; ++t) o[s][t] = (f32x4){0.f, 0.f, 0.f, 0.f};
  float l_part[2][4] = {{0.f, 0.f, 0.f, 0.f}, {0.f, 0.f, 0.f, 0.f}};

  const int srow = tid >> 3;               // 0..31 staging row-within-call
  const int sch = (tid & 7) ^ (srow & 7);  // logical chunk to fetch
  const int ph0 = (quad ^ (l15 & 7)) * 8;  // frag-read physical chunk offset

  // prologue: stage first tile into buffer 0
#pragma unroll
  for (int c = 0; c < 2; ++c) {
    load_lds16(bq + (size_t)(kbeg * 64 + c * 32 + srow) * QPITCH + 512 + h * 64 + sch * 8,
               &Ks[0][c * 2048 + wave * 512]);
    load_lds16(bvt + (size_t)(c * 32 + srow) * SEQ_T + kbeg * 64 + sch * 8,
               &Vts[0][c * 2048 + wave * 512]);
  }

  for (int kt = kbeg; kt <= kend; ++kt) {
    const int k0 = kt * 64;
    const int cur = (kt - kbeg) & 1;
    __syncthreads();   // drains loads issued one full iteration ago
    if (kt < kend) {   // stage next tile into the other buffer (post-barrier)
      const int kn = (kt + 1) * 64;
      const int nxt = cur ^ 1;
#pragma unroll
      for (int c = 0; c < 2; ++c) {
        load_lds16(bq + (size_t)(kn + c * 32 + srow) * QPITCH + 512 + h * 64 + sch * 8,
                   &Ks[nxt][c * 2048 + wave * 512]);
        load_lds16(bvt + (size_t)(c * 32 + srow) * SEQ_T + kn + sch * 8,
                   &Vts[nxt][c * 2048 + wave * 512]);
      }
    }

    const unsigned short* ksb = Ks[cur];
    const unsigned short* vsb = Vts[cur];
    const bool needMask = (k0 + 63) > q0;

    // ---- K B-frags once (shared by both strips)
    short8 bk[4][2];
#pragma unroll
    for (int t = 0; t < 4; ++t) {
      const unsigned short* kp = &ksb[(l15 + 16 * t) * 64];
      bk[t][0] = *(const short8*)(kp + ph0);
      bk[t][1] = *(const short8*)(kp + (ph0 ^ 32));
    }

    // ---- per strip: S = Q K^T -> exp2 -> packed P store
#pragma unroll
    for (int s = 0; s < 2; ++s) {
      f32x4 pr[4];
#pragma unroll
      for (int t = 0; t < 4; ++t) {
        f32x4 sv = (f32x4){0.f, 0.f, 0.f, 0.f};
        sv = __builtin_amdgcn_mfma_f32_16x16x32_bf16(aq[s][0], bk[t][0], sv, 0, 0, 0);
        sv = __builtin_amdgcn_mfma_f32_16x16x32_bf16(aq[s][1], bk[t][1], sv, 0, 0, 0);
        pr[t] = sv;
      }
      const int rbase = s * 64 + wave * 16 + quad * 4;
#pragma unroll
      for (int t = 0; t < 4; ++t)
#pragma unroll
        for (int r = 0; r < 4; ++r) {
          float p = __builtin_amdgcn_exp2f(pr[t][r]);
          if (needMask)
            p = (k0 + 16 * t + l15 <= q0 + rbase + r) ? p : 0.f;
          l_part[s][r] += p;
          pr[t][r] = p;
        }
      // pack 4 t-values (contiguous permuted cols 4*l15..+4) -> b64 store
#pragma unroll
      for (int r = 0; r < 4; ++r) {
        uint2 w;
        w.x = __builtin_amdgcn_perm(__float_as_uint(pr[1][r]), __float_as_uint(pr[0][r]), 0x07060302u);
        w.y = __builtin_amdgcn_perm(__float_as_uint(pr[3][r]), __float_as_uint(pr[2][r]), 0x07060302u);
        *(uint2*)&Ps[(rbase + r) * 72 + 4 * l15] = w;
      }
    }

    // ---- V^T B-frags + P A-frags (wave-internal dep for Ps; no barrier)
    short8 bv[4][2];
#pragma unroll
    for (int t = 0; t < 4; ++t) {
      const unsigned short* vp = &vsb[(l15 + 16 * t) * 64];
      bv[t][0] = *(const short8*)(vp + ph0);
      bv[t][1] = *(const short8*)(vp + (ph0 ^ 32));
    }
    short8 ap[2][2];
#pragma unroll
    for (int s = 0; s < 2; ++s) {
      const unsigned short* pp = &Ps[(s * 64 + wave * 16 + l15) * 72];
      ap[s][0] = *(const short8*)(pp + quad * 8);
      ap[s][1] = *(const short8*)(pp + 32 + quad * 8);
    }

    // ---- O += P V
#pragma unroll
    for (int t = 0; t < 4; ++t)
#pragma unroll
      for (int s = 0; s < 2; ++s) {
        o[s][t] = __builtin_amdgcn_mfma_f32_16x16x32_bf16(ap[s][0], bv[t][0], o[s][t], 0, 0, 0);
        o[s][t] = __builtin_amdgcn_mfma_f32_16x16x32_bf16(ap[s][1], bv[t][1], o[s][t], 0, 0, 0);
      }
  }

  // ---- epilogue: bf16 partial O + per-row l (division happens in out_merge)
  unsigned short* pb = kh ? pbuf1 : pbuf0;
#pragma unroll
  for (int s = 0; s < 2; ++s) {
#pragma unroll
    for (int r = 0; r < 4; ++r) {
      float l = rsum16(l_part[s][r]);
      const int trow = q0 + s * 64 + wave * 16 + quad * 4 + r;
      if (l15 == 0) lbuf[kh * (NBH * SEQ_T) + bh * SEQ_T + trow] = l;
      const size_t base = ((size_t)bh * SEQ_T + trow) * DHEAD;
#pragma unroll
      for (int t = 0; t < 4; ++t) pb[base + l15 + 16 * t] = f2bf(o[s][t][r]);
    }
  }
}

// ---------------------------------------------------------------------------
// Kernel 4 (fused): attn_vec = (O0+O1)/(l0+l1); out = mean_h(attn_vec) @ W_out
// ---------------------------------------------------------------------------
__global__ __launch_bounds__(256) void out_merge(const unsigned short* __restrict__ pbuf0,
                                                 const unsigned short* __restrict__ pbuf1,
                                                 const float* __restrict__ lbuf,
                                                 const float* __restrict__ Wout,
                                                 float* __restrict__ attnv,
                                                 float* __restrict__ out) {
  const int row0 = blockIdx.x * 16;   // global row = b*2048 + t
  const int tid = threadIdx.x;
  __shared__ float Ms[16][64];

  {
    const int lr = tid >> 4;
    const int d0 = (tid & 15) * 4;
    const int row = row0 + lr;
    const int b = row >> 11;
    const int t = row & 2047;
    float s0 = 0.f, s1 = 0.f, s2 = 0.f, s3 = 0.f;
#pragma unroll
    for (int hh = 0; hh < NHEAD; ++hh) {
      const size_t ridx = (size_t)(b * NHEAD + hh) * SEQ_T + t;
      const float inv = 1.0f / (lbuf[ridx] + lbuf[NBH * SEQ_T + ridx]);
      const size_t idx = ridx * DHEAD + d0;
      ushort4 A = *(const ushort4*)(pbuf0 + idx);
      ushort4 B = *(const ushort4*)(pbuf1 + idx);
      float4 m;
      m.x = (bf2f(A.x) + bf2f(B.x)) * inv;
      m.y = (bf2f(A.y) + bf2f(B.y)) * inv;
      m.z = (bf2f(A.z) + bf2f(B.z)) * inv;
      m.w = (bf2f(A.w) + bf2f(B.w)) * inv;
      *(float4*)(attnv + idx) = m;
      s0 += m.x; s1 += m.y; s2 += m.z; s3 += m.w;
    }
    Ms[lr][d0 + 0] = s0 * 0.125f;
    Ms[lr][d0 + 1] = s1 * 0.125f;
    Ms[lr][d0 + 2] = s2 * 0.125f;
    Ms[lr][d0 + 3] = s3 * 0.125f;
  }
  __syncthreads();

  const int c0 = tid * 2;
  float a0[16], a1[16];
#pragma unroll
  for (int i = 0; i < 16; ++i) { a0[i] = 0.f; a1[i] = 0.f; }

  for (int d = 0; d < 64; ++d) {
    float2 w = *(const float2*)(Wout + (size_t)d * HIDDEN + c0);
#pragma unroll
    for (int lr = 0; lr < 16; ++lr) {
      float m = Ms[lr][d];
      a0[lr] += m * w.x;
      a1[lr] += m * w.y;
    }
  }
#pragma unroll
  for (int lr = 0; lr < 16; ++lr) {
    float2 v = make_float2(a0[lr], a1[lr]);
    *(float2*)(out + (size_t)(row0 + lr) * HIDDEN + c0) = v;
  }
}

// ---------------------------------------------------------------------------
extern "C" void kernel_launch(void* const* d_in, const int* in_sizes, int n_in,
                              void* d_out, int out_size, void* d_ws, size_t ws_size,
                              hipStream_t stream) {
  const float* x     = (const float*)d_in[0];   // (4,2048,512)
  const float* W_qkv = (const float*)d_in[1];   // (512,1088)
  const float* W_out = (const float*)d_in[2];   // (64,512)

  float* out      = (float*)d_out;                              // (4,2048,512)
  float* attn_vec = out + (size_t)BATCH * SEQ_T * HIDDEN;       // (4,8,2048,64)

  unsigned short* qkv  = (unsigned short*)d_ws;                 // 8192x1152 bf16 = 18.9 MB
  unsigned short* vt   = qkv + (size_t)NROWS * QPITCH;          // 1.0 MB bf16
  unsigned short* xb   = vt + (size_t)BATCH * DHEAD * SEQ_T;    // 8.4 MB bf16
  unsigned short* Wt   = xb + (size_t)NROWS * HIDDEN;           // 1152x512 bf16 = 1.2 MB
  unsigned short* pbuf0 = Wt + (size_t)QPITCH * HIDDEN;         // 8.4 MB bf16 partial O
  unsigned short* pbuf1 = pbuf0 + (size_t)NBH * SEQ_T * DHEAD;  // 8.4 MB bf16 partial O
  float*          lbuf  = (float*)(pbuf1 + (size_t)NBH * SEQ_T * DHEAD);  // 0.5 MB

  prep<<<dim3(2048 + 136 + 8), 256, 0, stream>>>(x, W_qkv, xb, Wt);
  qkv_mfma<<<dim3(576), 256, 0, stream>>>(xb, Wt, qkv);
  v_transpose<<<dim3(BATCH * NT), 256, 0, stream>>>(qkv, vt);
  attn_pass<<<dim3(NBH, 32), 256, 0, stream>>>(qkv, vt, pbuf0, pbuf1, lbuf);
  out_merge<<<dim3(512), 256, 0, stream>>>(pbuf0, pbuf1, lbuf, W_out, attn_vec, out);
}